// Round 1
// baseline (1221.784 us; speedup 1.0000x reference)
//
#include <hip/hip_runtime.h>
#include <hip/hip_bf16.h>

// Problem constants
#define IN_SIZE 128
#define HID    64
#define BATCH  32
#define D1     129                 // IN_SIZE+1
#define NSLAB  (D1*D1)             // 16641 (i,j) slabs
#define FUSED  (D1*D1*D1)          // 2146689 rows of W1

// ws layout (floats):
//   thT  [129][32]      @ 0            (4128 floats)
//   avT  [16641][32]    @ 4128         (532512 floats)
//   y1   [32][64]       @ 536640       (2048 floats)
#define THT_OFF 0
#define AVT_OFF 4128
#define Y1_OFF  536640

// ---------------- K1: precompute thT, avT, init y1 with b1 ----------------
__global__ void k_prep(const float* __restrict__ l1, const float* __restrict__ a1,
                       const float* __restrict__ v1, const float* __restrict__ b1,
                       float* __restrict__ thT, float* __restrict__ avT,
                       float* __restrict__ y1) {
    int idx = blockIdx.x * blockDim.x + threadIdx.x;
    if (idx < NSLAB * BATCH) {
        int ij = idx >> 5, b = idx & 31;
        int i = ij / D1, j = ij - i * D1;
        float ah = (i == 0) ? 1.f : a1[b * IN_SIZE + i - 1];
        float vh = (j == 0) ? 1.f : v1[b * IN_SIZE + j - 1];
        avT[idx] = ah * vh;
    }
    if (idx < D1 * BATCH) {
        int k = idx >> 5, b = idx & 31;
        thT[idx] = (k == 0) ? 1.f : l1[b * IN_SIZE + k - 1];
    }
    if (idx < BATCH * HID) {
        y1[idx] = b1[idx & (HID - 1)];
    }
}

// ---------------- K2: stream W1, accumulate y1 ----------------
// lane = h (64 cols). Per row: 1 coalesced global_load_dword (256B/wave),
// 32 v_fmac with wave-uniform th operands (SMEM s_load path).
// Work unit = half k-slab (65 or 64 rows) for load balance.
__global__ __launch_bounds__(256, 3)
void k_main(const float* __restrict__ W1, const float* __restrict__ thT,
            const float* __restrict__ avT, float* __restrict__ y1) {
    const int lane   = threadIdx.x & 63;
    const int wlocal = threadIdx.x >> 6;
    const int wave   = blockIdx.x * 4 + wlocal;
    const int nw     = gridDim.x * 4;

    float acc[BATCH];
#pragma unroll
    for (int b = 0; b < BATCH; ++b) acc[b] = 0.f;

    const int NU = NSLAB * 2;
    for (int u = wave; u < NU; u += nw) {
        const int ij   = u >> 1;
        const int half = u & 1;
        const int k0   = half ? 65 : 0;
        const int k1   = half ? 129 : 65;

        const float* wp = W1 + (long)(ij * D1 + k0) * HID + lane;
        float M[BATCH];
#pragma unroll
        for (int b = 0; b < BATCH; ++b) M[b] = 0.f;

#pragma unroll 2
        for (int k = k0; k < k1; ++k) {
            float w = __builtin_nontemporal_load(wp);
            wp += HID;
            const float* t = thT + k * BATCH;   // wave-uniform -> s_load
#pragma unroll
            for (int b = 0; b < BATCH; ++b)
                M[b] = __builtin_fmaf(t[b], w, M[b]);
        }

        const float* av = avT + ij * BATCH;     // wave-uniform -> s_load
#pragma unroll
        for (int b = 0; b < BATCH; ++b)
            acc[b] = __builtin_fmaf(av[b], M[b], acc[b]);
    }

    // Block reduce (4 waves) then one atomicAdd per element.
    __shared__ float red[4][BATCH * HID];
#pragma unroll
    for (int b = 0; b < BATCH; ++b) red[wlocal][b * HID + lane] = acc[b];
    __syncthreads();
    for (int e = threadIdx.x; e < BATCH * HID; e += 256) {
        float v = red[0][e] + red[1][e] + red[2][e] + red[3][e];
        atomicAdd(&y1[e], v);
    }
}

// ---------------- K3: tiny MLP tail ----------------
__global__ void k_mlp(const float* __restrict__ y1, const float* __restrict__ W2,
                      const float* __restrict__ b2, const float* __restrict__ W3,
                      const float* __restrict__ b3, float* __restrict__ out) {
    __shared__ float y2s[BATCH * HID];
    int t = threadIdx.x;
    for (int e = t; e < BATCH * HID; e += 256) {
        int b = e >> 6, h = e & 63;
        float s = b2[h];
        for (int k = 0; k < HID; ++k)
            s = __builtin_fmaf(y1[b * HID + k], W2[k * HID + h], s);
        y2s[e] = tanhf(s);
    }
    __syncthreads();
    if (t < BATCH) {
        float s = b3[0];
        for (int h = 0; h < HID; ++h)
            s = __builtin_fmaf(y2s[t * HID + h], W3[h], s);
        out[t] = fmaxf(s, 0.f);
    }
}

extern "C" void kernel_launch(void* const* d_in, const int* in_sizes, int n_in,
                              void* d_out, int out_size, void* d_ws, size_t ws_size,
                              hipStream_t stream) {
    const float* l1 = (const float*)d_in[0];
    const float* a1 = (const float*)d_in[1];
    const float* v1 = (const float*)d_in[2];
    const float* W1 = (const float*)d_in[3];
    const float* b1 = (const float*)d_in[4];
    const float* W2 = (const float*)d_in[5];
    const float* b2 = (const float*)d_in[6];
    const float* W3 = (const float*)d_in[7];
    const float* b3 = (const float*)d_in[8];
    float* out = (float*)d_out;

    float* ws  = (float*)d_ws;
    float* thT = ws + THT_OFF;
    float* avT = ws + AVT_OFF;
    float* y1  = ws + Y1_OFF;

    // K1: prep (covers avT's 532512 elements)
    int prep_threads = NSLAB * BATCH;
    k_prep<<<(prep_threads + 255) / 256, 256, 0, stream>>>(l1, a1, v1, b1, thT, avT, y1);

    // K2: main stream. 768 blocks = 3 blocks/CU on 256 CUs.
    k_main<<<768, 256, 0, stream>>>(W1, thT, avT, y1);

    // K3: MLP tail
    k_mlp<<<1, 256, 0, stream>>>(y1, W2, b2, W3, b3, out);
}